// Round 15
// baseline (349.800 us; speedup 1.0000x reference)
//
#include <hip/hip_runtime.h>

typedef _Float16 half_t;
typedef _Float16 half8 __attribute__((ext_vector_type(8)));
typedef float f32x4 __attribute__((ext_vector_type(4)));

#define D_EMBED   1024
#define D_CROSS   768
#define N_HEADS   8
#define D_HEAD    128
#define BATCH     8
#define SEQ_Q     4096
#define SEQ_KV    77
#define SKV_PAD   80
#define NKV       (N_HEADS*SKV_PAD)     /* 640 */
#define NKV_PAD   768                   /* Bt1 row-dim padding (rows 640..767 never read) */
#define M_Q       (BATCH*SEQ_Q)         /* 32768 */

// ---------------- workspace layout (bytes) ----------------
#define WS_S     ((size_t)0)                                   // (unused)
#define WS_WQC   (WS_S    + (size_t)M_Q*NKV*2)
#define WS_WOT   (WS_WQC  + (size_t)D_EMBED*D_EMBED*2)
#define WS_WKVT  (WS_WOT  + (size_t)D_EMBED*D_EMBED*2)
#define WS_YH    (WS_WKVT + (size_t)2*D_EMBED*D_CROSS*2)
#define WS_KV    (WS_YH   + (size_t)BATCH*SKV_PAD*D_CROSS*2)
#define WS_BKV   (WS_KV   + (size_t)BATCH*SKV_PAD*2*D_EMBED*2)
#define WS_BT1   (WS_BKV  + (size_t)2*D_EMBED*4)               // W1^T fp16 [8][768][1024] 3-bit swz, 2048B rows
#define WS_BT2   (WS_BT1  + (size_t)BATCH*NKV_PAD*D_EMBED*2)   // W2^T fp16 [8][1024][640] 3-bit swz, 1280B rows
#define WS_C1    (WS_BT2  + (size_t)BATCH*D_EMBED*NKV*2)       // c1 fp32 [8][640]

#define ATTN_SCALE 0.08838834764831845f

__device__ __forceinline__ void gload_lds16(const void* g, void* lds) {
  __builtin_amdgcn_global_load_lds(
      (const __attribute__((address_space(1))) unsigned int*)g,
      (__attribute__((address_space(3))) unsigned int*)lds, 16, 0, 0);
}
__device__ __forceinline__ void BAR() {
  __builtin_amdgcn_s_barrier();
  __builtin_amdgcn_sched_barrier(0);
}

// ---------------- prep kernels ----------------
__global__ void cast_f32_f16(const float* __restrict__ src, half_t* __restrict__ dst) {
  int i = blockIdx.x * 256 + threadIdx.x;
  f32x4 a = *(const f32x4*)(src + (size_t)i*8);
  f32x4 b = *(const f32x4*)(src + (size_t)i*8 + 4);
  half8 h;
#pragma unroll
  for (int j = 0; j < 4; ++j) { h[j] = (half_t)a[j]; h[j+4] = (half_t)b[j]; }
  *(half8*)(dst + (size_t)i*8) = h;
}

__global__ void transpose_f32f16(const float* __restrict__ src, half_t* __restrict__ dst,
                                 int K, int N) {
  __shared__ float tile[32][33];
  int n0 = blockIdx.x * 32, k0 = blockIdx.y * 32;
  int tx = threadIdx.x, ty = threadIdx.y;
#pragma unroll
  for (int j = 0; j < 4; ++j)
    tile[ty + j*8][tx] = src[(size_t)(k0 + ty + j*8)*N + n0 + tx];
  __syncthreads();
#pragma unroll
  for (int j = 0; j < 4; ++j)
    dst[(size_t)(n0 + ty + j*8)*K + k0 + tx] = (half_t)tile[tx][ty + j*8];
}

__global__ void convert_pad_y(const float* __restrict__ y, half_t* __restrict__ yh) {
  int idx = blockIdx.x * 256 + threadIdx.x;
  int r = idx / D_CROSS, col = idx - r*D_CROSS;
  int b = r / SKV_PAD, s = r - b*SKV_PAD;
  yh[idx] = (s < SEQ_KV) ? (half_t)y[(size_t)(b*SEQ_KV + s)*D_CROSS + col] : (half_t)0.f;
}

__global__ void concat_bias(const float* __restrict__ bk, const float* __restrict__ bv,
                            float* __restrict__ bkv) {
  int i = blockIdx.x * 256 + threadIdx.x;
  bkv[i] = (i < D_EMBED) ? bk[i] : bv[i - D_EMBED];
}

// ---------------- 128x128 GEMM — K/V projection (R7-verified) ----------------
__global__ __launch_bounds__(256, 3)
void gemm_kv(const half_t* __restrict__ A, const half_t* __restrict__ Bt,
             const float* __restrict__ bias, half_t* __restrict__ C,
             int M, int N, int K) {
  __shared__ half_t As[3][128*32];
  __shared__ half_t Bs[2][128*32];
  const int tid = threadIdx.x;
  const int l = tid & 63, w = tid >> 6;
  const int l4 = l & 15, lh = l >> 4;
  const int bn0 = blockIdx.x * 128, bm0 = blockIdx.y * 128;
  const int wr = w >> 1, wc = w & 1;
  const int rslot = lh << 4;
  f32x4 acc[4][4] = {};
  const int nk = K >> 5;
  const int srow = w*16 + (l >> 2);
  const int scol = (l & 3)*8;

  auto stageB = [&](int kt, int bb) {
    const half_t* g = Bt + (size_t)(bn0 + srow)*K + scol + kt*32;
    gload_lds16(g,                 (char*)Bs[bb] + w*1024);
    gload_lds16(g + (size_t)64*K,  (char*)Bs[bb] + 4096 + w*1024);
  };
  auto stageA = [&](int kt, int bb) {
    const half_t* g = A + (size_t)(bm0 + srow)*K + scol + kt*32;
    gload_lds16(g,                 (char*)As[bb] + w*1024);
    gload_lds16(g + (size_t)64*K,  (char*)As[bb] + 4096 + w*1024);
  };
  auto compute = [&](int ab, int bb) {
    half8 af[4], bf[4];
#pragma unroll
    for (int m = 0; m < 4; ++m)
      af[m] = *(const half8*)((const char*)As[ab] + (size_t)(wr*64 + m*16 + l4)*64 + rslot);
#pragma unroll
    for (int n = 0; n < 4; ++n)
      bf[n] = *(const half8*)((const char*)Bs[bb] + (size_t)(wc*64 + n*16 + l4)*64 + rslot);
#pragma unroll
    for (int m = 0; m < 4; ++m)
#pragma unroll
      for (int n = 0; n < 4; ++n)
        acc[m][n] = __builtin_amdgcn_mfma_f32_16x16x32_f16(af[m], bf[n], acc[m][n], 0, 0, 0);
  };

  stageA(0, 0); stageA(1, 1); stageB(0, 0);
  asm volatile("s_waitcnt vmcnt(0)" ::: "memory");
  BAR();
  int aCur = 0, aP2 = 2;
  for (int t = 0; t < nk; ++t) {
    if (t + 1 < nk) stageB(t + 1, (t + 1) & 1);
    if (t + 2 < nk) stageA(t + 2, aP2);
    compute(aCur, t & 1);
    if (t + 1 < nk) {
      if (t + 2 < nk) { asm volatile("s_waitcnt vmcnt(2)" ::: "memory"); }
      else            { asm volatile("s_waitcnt vmcnt(0)" ::: "memory"); }
      BAR();
    }
    aCur = (aCur == 2) ? 0 : aCur + 1;
    aP2  = (aP2  == 2) ? 0 : aP2  + 1;
  }

  const int cb = bn0 + wc*64, rb = bm0 + wr*64;
#pragma unroll
  for (int n = 0; n < 4; ++n) {
    const int col = cb + n*16 + l4;
    const float bvv = bias[col];
#pragma unroll
    for (int m = 0; m < 4; ++m)
#pragma unroll
      for (int j = 0; j < 4; ++j)
        C[(size_t)(rb + m*16 + lh*4 + j)*N + col] = (half_t)(acc[m][n][j] + bvv);
  }
}

// ---------------- builders (R11/R13-verified) ----------------
__global__ __launch_bounds__(256, 2)
void w1_build(const half_t* __restrict__ kvb, const half_t* __restrict__ Wqc,
              half_t* __restrict__ Bt1) {
  __shared__ half_t K_lds[80*136];
  const int blk = blockIdx.x;
  const int b = blk >> 3, h = blk & 7;
  const int tid = threadIdx.x;
  const int l = tid & 63, w = tid >> 6;
  const int l4 = l & 15, lh = l >> 4;
  for (int i = tid; i < 80*16; i += 256) {
    int s = i >> 4, d = (i & 15) << 3;
    *(half8*)(K_lds + s*136 + d) =
        *(const half8*)(kvb + (size_t)(b*SKV_PAD + s)*2048 + h*128 + d);
  }
  __syncthreads();
  for (int c = 0; c < 4; ++c) {
    f32x4 acc[5][4] = {};
#pragma unroll
    for (int kt = 0; kt < 4; ++kt) {
      half8 af[5], bf[4];
#pragma unroll
      for (int m = 0; m < 5; ++m)
        af[m] = *(const half8*)(K_lds + (size_t)(m*16 + l4)*136 + kt*32 + lh*8);
#pragma unroll
      for (int n = 0; n < 4; ++n)
        bf[n] = *(const half8*)(Wqc + (size_t)(w*256 + c*64 + n*16 + l4)*1024 + h*128 + kt*32 + lh*8);
#pragma unroll
      for (int m = 0; m < 5; ++m)
#pragma unroll
        for (int n = 0; n < 4; ++n)
          acc[m][n] = __builtin_amdgcn_mfma_f32_16x16x32_f16(af[m], bf[n], acc[m][n], 0, 0, 0);
    }
#pragma unroll
    for (int n = 0; n < 4; ++n) {
      const int colk = w*256 + c*64 + n*16 + l4;
#pragma unroll
      for (int m = 0; m < 5; ++m)
#pragma unroll
        for (int j = 0; j < 4; ++j) {
          const int r = h*SKV_PAD + m*16 + lh*4 + j;
          size_t byte = ((size_t)(b*NKV_PAD + r))*2048 + (size_t)(colk >> 6)*128
                        + ((size_t)(((colk >> 3) & 7) ^ (r & 7)) << 4) + ((colk & 7) << 1);
          *(half_t*)((char*)Bt1 + byte) = (half_t)(acc[m][n][j]*ATTN_SCALE);
        }
    }
  }
}

__global__ __launch_bounds__(256, 2)
void w2_build(const half_t* __restrict__ kvb, const half_t* __restrict__ Wot,
              half_t* __restrict__ Bt2) {
  __shared__ half_t V_lds[80*136];
  const int blk = blockIdx.x;
  const int b = blk >> 3, h = blk & 7;
  const int tid = threadIdx.x;
  const int l = tid & 63, w = tid >> 6;
  const int l4 = l & 15, lh = l >> 4;
  for (int i = tid; i < 80*16; i += 256) {
    int s = i >> 4, d = (i & 15) << 3;
    *(half8*)(V_lds + s*136 + d) =
        *(const half8*)(kvb + (size_t)(b*SKV_PAD + s)*2048 + 1024 + h*128 + d);
  }
  __syncthreads();
  for (int c = 0; c < 4; ++c) {
    f32x4 acc[4][5] = {};
#pragma unroll
    for (int kt = 0; kt < 4; ++kt) {
      half8 af[4], bf[5];
#pragma unroll
      for (int m = 0; m < 4; ++m)
        af[m] = *(const half8*)(Wot + (size_t)(w*256 + c*64 + m*16 + l4)*1024 + h*128 + kt*32 + lh*8);
#pragma unroll
      for (int n = 0; n < 5; ++n)
        bf[n] = *(const half8*)(V_lds + (size_t)(n*16 + l4)*136 + kt*32 + lh*8);
#pragma unroll
      for (int m = 0; m < 4; ++m)
#pragma unroll
        for (int n = 0; n < 5; ++n)
          acc[m][n] = __builtin_amdgcn_mfma_f32_16x16x32_f16(af[m], bf[n], acc[m][n], 0, 0, 0);
    }
#pragma unroll
    for (int m = 0; m < 4; ++m) {
#pragma unroll
      for (int j = 0; j < 4; ++j) {
        const int nrow = w*256 + c*64 + m*16 + lh*4 + j;
        const size_t rowbase = ((size_t)(b*1024 + nrow))*1280;
#pragma unroll
        for (int n = 0; n < 5; ++n) {
          const int cc = h*80 + n*16 + l4;
          size_t byte = rowbase + (size_t)(cc >> 6)*128
                        + ((size_t)(((cc >> 3) & 7) ^ (nrow & 7)) << 4) + ((cc & 7) << 1);
          *(half_t*)((char*)Bt2 + byte) = (half_t)acc[m][n][j];
        }
      }
    }
  }
}

__global__ void c1_build(const half_t* __restrict__ kvb, const float* __restrict__ bq,
                         float* __restrict__ c1) {
  int idx = blockIdx.x * 256 + threadIdx.x;
  int b = idx / NKV, n = idx - b*NKV;
  int h = n / SKV_PAD, s = n - h*SKV_PAD;
  const half_t* kp = kvb + (size_t)(b*SKV_PAD + s)*2048 + h*128;
  float acc = 0.f;
#pragma unroll 8
  for (int d = 0; d < 128; ++d) acc += bq[h*128 + d] * (float)kp[d];
  c1[idx] = acc * ATTN_SCALE;
}

// ---------------- FUSED v3: 32-row tiles -> 48 KB LDS -> 2 blocks/CU ----------------
// 1024 blocks (8 XCDs x 128; one batch per XCD). 512 thr / 8 waves; wave w = head w
// in S phase (sacc[2][5]), out cols w*128 in P phase (2 passes of oacc[2][4]).
// All swizzle math identical to R13/R14-verified paths; only m-extent and mapping changed.
__global__ __launch_bounds__(512, 2)
void fused_sv(const float* __restrict__ X, const half_t* __restrict__ Bt1,
              const float* __restrict__ c1, const half_t* __restrict__ Bt2,
              const float* __restrict__ bo, float* __restrict__ out) {
  __shared__ half_t S_lds[32*640];       // 40 KB
  __shared__ half_t x_lds[2][32*64];     // 2 x 4 KB
  const int tid = threadIdx.x;
  const int l = tid & 63, w = tid >> 6;
  const int l4 = l & 15, lh = l >> 4;
  const int k7 = l4 & 7;

  const int lin = ((int)blockIdx.x & 7)*128 + ((int)blockIdx.x >> 3);
  const int batch = lin >> 7;
  const int row0 = batch*SEQ_Q + (lin & 127)*32;
  const char* W1 = (const char*)(Bt1 + (size_t)batch*NKV_PAD*1024);
  const char* W2 = (const char*)(Bt2 + (size_t)batch*1024*NKV);
  const float* c1b = c1 + batch*NKV;

  // ================= S phase =================
  f32x4 sacc[2][5] = {};
  const int nfb = w*5;

  // x staging: thread -> row tid>>4 (0..31), 4 floats at col (tid&15)*4
  const int xrow = tid >> 4, xc4 = (tid & 15)*4;
  const float* xg = X + (size_t)(row0 + xrow)*1024 + xc4;
  f32x4 xa;
  auto xload = [&](int kc) { xa = *(const f32x4*)(xg + kc*64); };
  auto xwrite = [&](int buf) {
    half_t h4[4];
#pragma unroll
    for (int e = 0; e < 4; ++e) h4[e] = (half_t)xa[e];
    // 8B write at k=xc4 within 128B row, 3-bit slot swizzle
    char* p = (char*)x_lds[buf] + xrow*128
              + ((((xc4 >> 3) & 7) ^ (xrow & 7)) << 4) + (xc4 & 7)*2;
    *(uint2*)p = *(const uint2*)h4;
  };

  half8 b0[5], b1[5];
  auto bload = [&](int t, half8* dst) {
    const int kc = t >> 1, kk = t & 1;
    const size_t koff = (size_t)kc*128 + (size_t)(((kk*4 + lh) ^ k7) << 4);
#pragma unroll
    for (int nf = 0; nf < 5; ++nf)
      dst[nf] = *(const half8*)(W1 + (size_t)((nfb + nf)*16 + l4)*2048 + koff);
  };
  auto smfma = [&](const half8* bf, int kc, int kk) {
    const char* xc = (const char*)x_lds[kc & 1];
    half8 af[2];
#pragma unroll
    for (int m = 0; m < 2; ++m)
      af[m] = *(const half8*)(xc + (size_t)(m*16 + l4)*128 + (((kk*4 + lh) ^ k7) << 4));
    __builtin_amdgcn_s_setprio(1);
#pragma unroll
    for (int nf = 0; nf < 5; ++nf)
#pragma unroll
      for (int m = 0; m < 2; ++m)
        sacc[m][nf] = __builtin_amdgcn_mfma_f32_16x16x32_f16(af[m], bf[nf], sacc[m][nf], 0, 0, 0);
    __builtin_amdgcn_s_setprio(0);
  };

  xload(0); xwrite(0);
  bload(0, b0);
  asm volatile("s_waitcnt lgkmcnt(0)" ::: "memory");
  BAR();

  for (int kc = 0; kc < 16; ++kc) {
    if (kc + 1 < 16) xload(kc + 1);            // issue early (T14)
    bload(2*kc + 1, b1);                        // prefetch next step's B
    smfma(b0, kc, 0);
    if (2*kc + 2 < 32) bload(2*kc + 2, b0);     // prefetch step after
    smfma(b1, kc, 1);
    if (kc + 1 < 16) {
      xwrite((kc + 1) & 1);                     // cvt + ds_write late
      asm volatile("s_waitcnt lgkmcnt(0)" ::: "memory");
      BAR();                                    // raw: B prefetches stay in flight
    }
  }

  // dump S-frags to S_lds (3-bit swizzle; verified)
#pragma unroll
  for (int nf = 0; nf < 5; ++nf) {
    const int col = (nfb + nf)*16 + l4;
#pragma unroll
    for (int m = 0; m < 2; ++m)
#pragma unroll
      for (int j = 0; j < 4; ++j) {
        const int row = m*16 + lh*4 + j;
        size_t byte = (size_t)row*1280 + (size_t)(col >> 6)*128
                      + ((size_t)(((col >> 3) & 7) ^ (row & 7)) << 4) + ((col & 7) << 1);
        *(half_t*)((char*)S_lds + byte) = (half_t)sacc[m][nf][j];
      }
  }
  asm volatile("s_waitcnt lgkmcnt(0)" ::: "memory");
  BAR();

  // ================= softmax in LDS (verified; 256 active threads) =================
  if (tid < 256) {
    const int row = tid >> 3, h = tid & 7;
    const int key = row & 7;
    char* base = (char*)S_lds + (size_t)row*1280;
    float fv[10][8];
    float mx = -1e30f;
#pragma unroll
    for (int i = 0; i < 10; ++i) {
      const int ls = h*10 + i;
      half8 v = *(const half8*)(base + (size_t)(ls >> 3)*128 + ((size_t)((ls & 7) ^ key) << 4));
      f32x4 ca = *(const f32x4*)(c1b + h*80 + i*8);
      f32x4 cb = *(const f32x4*)(c1b + h*80 + i*8 + 4);
#pragma unroll
      for (int j = 0; j < 8; ++j) {
        const float cc = (j < 4) ? ca[j] : cb[j - 4];
        const float sv = (float)v[j] + cc;
        const bool ok = (i*8 + j) < SEQ_KV;
        fv[i][j] = ok ? sv : -1e30f;
        if (ok) mx = fmaxf(mx, sv);
      }
    }
    float sm = 0.f;
#pragma unroll
    for (int i = 0; i < 10; ++i)
#pragma unroll
      for (int j = 0; j < 8; ++j) { float e = __expf(fv[i][j] - mx); sm += e; fv[i][j] = e; }
    const float inv = 1.f / sm;
#pragma unroll
    for (int i = 0; i < 10; ++i) {
      const int ls = h*10 + i;
      half8 t;
#pragma unroll
      for (int j = 0; j < 8; ++j) t[j] = (half_t)(fv[i][j] * inv);
      *(half8*)(base + (size_t)(ls >> 3)*128 + ((size_t)((ls & 7) ^ key) << 4)) = t;
    }
  }
  asm volatile("s_waitcnt lgkmcnt(0)" ::: "memory");
  BAR();

  // ================= P phase: 2 passes of 4 n-frags, depth-1 B prefetch =================
#pragma unroll 1
  for (int pass = 0; pass < 2; ++pass) {
    f32x4 oacc[2][4] = {};
    half8 p0[4], p1[4];
    const int ncb = w*128 + pass*64;
    auto pbload = [&](int ks, half8* dst) {
      const size_t koff = (size_t)(ks >> 1)*128 + (size_t)((((ks & 1)*4 + lh) ^ k7) << 4);
#pragma unroll
      for (int nf = 0; nf < 4; ++nf)
        dst[nf] = *(const half8*)(W2 + (size_t)(ncb + nf*16 + l4)*1280 + koff);
    };
    auto pmfma = [&](const half8* bf, int ks) {
      const size_t koff = (size_t)(ks >> 1)*128 + (size_t)((((ks & 1)*4 + lh) ^ k7) << 4);
      half8 af[2];
#pragma unroll
      for (int m = 0; m < 2; ++m)
        af[m] = *(const half8*)((const char*)S_lds + (size_t)(m*16 + l4)*1280 + koff);
      __builtin_amdgcn_s_setprio(1);
#pragma unroll
      for (int nf = 0; nf < 4; ++nf)
#pragma unroll
        for (int m = 0; m < 2; ++m)
          oacc[m][nf] = __builtin_amdgcn_mfma_f32_16x16x32_f16(af[m], bf[nf], oacc[m][nf], 0, 0, 0);
      __builtin_amdgcn_s_setprio(0);
    };

    pbload(0, p0);
    for (int ks = 0; ks < 20; ks += 2) {
      pbload(ks + 1, p1);
      pmfma(p0, ks);
      if (ks + 2 < 20) pbload(ks + 2, p0);
      pmfma(p1, ks + 1);
    }

#pragma unroll
    for (int nf = 0; nf < 4; ++nf) {
      const int col = ncb + nf*16 + l4;
      const float bvv = bo[col];
#pragma unroll
      for (int m = 0; m < 2; ++m)
#pragma unroll
        for (int j = 0; j < 4; ++j) {
          const int row = row0 + m*16 + lh*4 + j;
          out[(size_t)row*1024 + col] = oacc[m][nf][j] + bvv;
        }
    }
  }
}

// ---------------- launch ----------------
extern "C" void kernel_launch(void* const* d_in, const int* in_sizes, int n_in,
                              void* d_out, int out_size, void* d_ws, size_t ws_size,
                              hipStream_t stream) {
  (void)in_sizes; (void)n_in; (void)out_size; (void)ws_size;
  const float* x  = (const float*)d_in[0];
  const float* y  = (const float*)d_in[1];
  const float* Wq = (const float*)d_in[2];
  const float* bq = (const float*)d_in[3];
  const float* Wk = (const float*)d_in[4];
  const float* bk = (const float*)d_in[5];
  const float* Wv = (const float*)d_in[6];
  const float* bv = (const float*)d_in[7];
  const float* Wo = (const float*)d_in[8];
  const float* bo = (const float*)d_in[9];

  char* ws = (char*)d_ws;
  half_t* Wqc  = (half_t*)(ws + WS_WQC);
  half_t* Wot  = (half_t*)(ws + WS_WOT);
  half_t* Wkvt = (half_t*)(ws + WS_WKVT);
  half_t* yh   = (half_t*)(ws + WS_YH);
  half_t* kvb  = (half_t*)(ws + WS_KV);
  float*  bkv  = (float*)(ws + WS_BKV);
  half_t* Bt1  = (half_t*)(ws + WS_BT1);
  half_t* Bt2  = (half_t*)(ws + WS_BT2);
  float*  c1   = (float*)(ws + WS_C1);

  dim3 tb(32, 8);
  cast_f32_f16<<<512, 256, 0, stream>>>(Wq, Wqc);
  transpose_f32f16<<<dim3(32, 32), tb, 0, stream>>>(Wo, Wot, 1024, 1024);
  transpose_f32f16<<<dim3(32, 24), tb, 0, stream>>>(Wk, Wkvt, 768, 1024);
  transpose_f32f16<<<dim3(32, 24), tb, 0, stream>>>(Wv, Wkvt + (size_t)1024*768, 768, 1024);
  convert_pad_y<<<BATCH*SKV_PAD*D_CROSS/256, 256, 0, stream>>>(y, yh);
  concat_bias<<<2*D_EMBED/256, 256, 0, stream>>>(bk, bv, bkv);

  // K/V projection
  gemm_kv<<<dim3(16, 5), 256, 0, stream>>>(yh, Wkvt, bkv, kvb, BATCH*SKV_PAD, 2048, 768);

  // folded-weight builders
  c1_build<<<BATCH*NKV/256, 256, 0, stream>>>(kvb, bq, c1);
  w1_build<<<BATCH*N_HEADS, 256, 0, stream>>>(kvb, Wqc, Bt1);
  w2_build<<<BATCH*N_HEADS, 256, 0, stream>>>(kvb, Wot, Bt2);

  // fused S-GEMM + softmax + out-GEMM (S stays in LDS), 32-row tiles
  fused_sv<<<1024, 512, 0, stream>>>(x, Bt1, c1, Bt2, bo, (float*)d_out);
}

// Round 16
// 297.376 us; speedup vs baseline: 1.1763x; 1.1763x over previous
//
#include <hip/hip_runtime.h>

typedef _Float16 half_t;
typedef _Float16 half8 __attribute__((ext_vector_type(8)));
typedef float f32x4 __attribute__((ext_vector_type(4)));

#define D_EMBED   1024
#define D_CROSS   768
#define N_HEADS   8
#define D_HEAD    128
#define BATCH     8
#define SEQ_Q     4096
#define SEQ_KV    77
#define SKV_PAD   80
#define NKV       (N_HEADS*SKV_PAD)     /* 640 */
#define NKV_PAD   768                   /* Bt1 row-dim padding (rows 640..767 never read) */
#define M_Q       (BATCH*SEQ_Q)         /* 32768 */

// ---------------- workspace layout (bytes) ----------------
#define WS_S     ((size_t)0)                                   // (unused)
#define WS_WQC   (WS_S    + (size_t)M_Q*NKV*2)
#define WS_WOT   (WS_WQC  + (size_t)D_EMBED*D_EMBED*2)
#define WS_WKVT  (WS_WOT  + (size_t)D_EMBED*D_EMBED*2)
#define WS_YH    (WS_WKVT + (size_t)2*D_EMBED*D_CROSS*2)
#define WS_KV    (WS_YH   + (size_t)BATCH*SKV_PAD*D_CROSS*2)
#define WS_BKV   (WS_KV   + (size_t)BATCH*SKV_PAD*2*D_EMBED*2)
#define WS_BT1   (WS_BKV  + (size_t)2*D_EMBED*4)               // W1^T fp16 [8][768][1024] 3-bit swz, 2048B rows
#define WS_BT2   (WS_BT1  + (size_t)BATCH*NKV_PAD*D_EMBED*2)   // W2^T fp16 [8][1024][640] 3-bit swz, 1280B rows
#define WS_C1    (WS_BT2  + (size_t)BATCH*D_EMBED*NKV*2)       // c1 fp32 [8][640]

#define ATTN_SCALE 0.08838834764831845f

__device__ __forceinline__ void gload_lds16(const void* g, void* lds) {
  __builtin_amdgcn_global_load_lds(
      (const __attribute__((address_space(1))) unsigned int*)g,
      (__attribute__((address_space(3))) unsigned int*)lds, 16, 0, 0);
}
__device__ __forceinline__ void BAR() {
  __builtin_amdgcn_s_barrier();
  __builtin_amdgcn_sched_barrier(0);
}

// ---------------- prep kernels ----------------
__global__ void cast_f32_f16(const float* __restrict__ src, half_t* __restrict__ dst) {
  int i = blockIdx.x * 256 + threadIdx.x;
  f32x4 a = *(const f32x4*)(src + (size_t)i*8);
  f32x4 b = *(const f32x4*)(src + (size_t)i*8 + 4);
  half8 h;
#pragma unroll
  for (int j = 0; j < 4; ++j) { h[j] = (half_t)a[j]; h[j+4] = (half_t)b[j]; }
  *(half8*)(dst + (size_t)i*8) = h;
}

__global__ void transpose_f32f16(const float* __restrict__ src, half_t* __restrict__ dst,
                                 int K, int N) {
  __shared__ float tile[32][33];
  int n0 = blockIdx.x * 32, k0 = blockIdx.y * 32;
  int tx = threadIdx.x, ty = threadIdx.y;
#pragma unroll
  for (int j = 0; j < 4; ++j)
    tile[ty + j*8][tx] = src[(size_t)(k0 + ty + j*8)*N + n0 + tx];
  __syncthreads();
#pragma unroll
  for (int j = 0; j < 4; ++j)
    dst[(size_t)(n0 + ty + j*8)*K + k0 + tx] = (half_t)tile[tx][ty + j*8];
}

__global__ void convert_pad_y(const float* __restrict__ y, half_t* __restrict__ yh) {
  int idx = blockIdx.x * 256 + threadIdx.x;
  int r = idx / D_CROSS, col = idx - r*D_CROSS;
  int b = r / SKV_PAD, s = r - b*SKV_PAD;
  yh[idx] = (s < SEQ_KV) ? (half_t)y[(size_t)(b*SEQ_KV + s)*D_CROSS + col] : (half_t)0.f;
}

__global__ void concat_bias(const float* __restrict__ bk, const float* __restrict__ bv,
                            float* __restrict__ bkv) {
  int i = blockIdx.x * 256 + threadIdx.x;
  bkv[i] = (i < D_EMBED) ? bk[i] : bv[i - D_EMBED];
}

// ---------------- 128x128 GEMM — K/V projection (R7-verified) ----------------
__global__ __launch_bounds__(256, 3)
void gemm_kv(const half_t* __restrict__ A, const half_t* __restrict__ Bt,
             const float* __restrict__ bias, half_t* __restrict__ C,
             int M, int N, int K) {
  __shared__ half_t As[3][128*32];
  __shared__ half_t Bs[2][128*32];
  const int tid = threadIdx.x;
  const int l = tid & 63, w = tid >> 6;
  const int l4 = l & 15, lh = l >> 4;
  const int bn0 = blockIdx.x * 128, bm0 = blockIdx.y * 128;
  const int wr = w >> 1, wc = w & 1;
  const int rslot = lh << 4;
  f32x4 acc[4][4] = {};
  const int nk = K >> 5;
  const int srow = w*16 + (l >> 2);
  const int scol = (l & 3)*8;

  auto stageB = [&](int kt, int bb) {
    const half_t* g = Bt + (size_t)(bn0 + srow)*K + scol + kt*32;
    gload_lds16(g,                 (char*)Bs[bb] + w*1024);
    gload_lds16(g + (size_t)64*K,  (char*)Bs[bb] + 4096 + w*1024);
  };
  auto stageA = [&](int kt, int bb) {
    const half_t* g = A + (size_t)(bm0 + srow)*K + scol + kt*32;
    gload_lds16(g,                 (char*)As[bb] + w*1024);
    gload_lds16(g + (size_t)64*K,  (char*)As[bb] + 4096 + w*1024);
  };
  auto compute = [&](int ab, int bb) {
    half8 af[4], bf[4];
#pragma unroll
    for (int m = 0; m < 4; ++m)
      af[m] = *(const half8*)((const char*)As[ab] + (size_t)(wr*64 + m*16 + l4)*64 + rslot);
#pragma unroll
    for (int n = 0; n < 4; ++n)
      bf[n] = *(const half8*)((const char*)Bs[bb] + (size_t)(wc*64 + n*16 + l4)*64 + rslot);
#pragma unroll
    for (int m = 0; m < 4; ++m)
#pragma unroll
      for (int n = 0; n < 4; ++n)
        acc[m][n] = __builtin_amdgcn_mfma_f32_16x16x32_f16(af[m], bf[n], acc[m][n], 0, 0, 0);
  };

  stageA(0, 0); stageA(1, 1); stageB(0, 0);
  asm volatile("s_waitcnt vmcnt(0)" ::: "memory");
  BAR();
  int aCur = 0, aP2 = 2;
  for (int t = 0; t < nk; ++t) {
    if (t + 1 < nk) stageB(t + 1, (t + 1) & 1);
    if (t + 2 < nk) stageA(t + 2, aP2);
    compute(aCur, t & 1);
    if (t + 1 < nk) {
      if (t + 2 < nk) { asm volatile("s_waitcnt vmcnt(2)" ::: "memory"); }
      else            { asm volatile("s_waitcnt vmcnt(0)" ::: "memory"); }
      BAR();
    }
    aCur = (aCur == 2) ? 0 : aCur + 1;
    aP2  = (aP2  == 2) ? 0 : aP2  + 1;
  }

  const int cb = bn0 + wc*64, rb = bm0 + wr*64;
#pragma unroll
  for (int n = 0; n < 4; ++n) {
    const int col = cb + n*16 + l4;
    const float bvv = bias[col];
#pragma unroll
    for (int m = 0; m < 4; ++m)
#pragma unroll
      for (int j = 0; j < 4; ++j)
        C[(size_t)(rb + m*16 + lh*4 + j)*N + col] = (half_t)(acc[m][n][j] + bvv);
  }
}

// ---------------- builders (R11/R13-verified) ----------------
__global__ __launch_bounds__(256, 2)
void w1_build(const half_t* __restrict__ kvb, const half_t* __restrict__ Wqc,
              half_t* __restrict__ Bt1) {
  __shared__ half_t K_lds[80*136];
  const int blk = blockIdx.x;
  const int b = blk >> 3, h = blk & 7;
  const int tid = threadIdx.x;
  const int l = tid & 63, w = tid >> 6;
  const int l4 = l & 15, lh = l >> 4;
  for (int i = tid; i < 80*16; i += 256) {
    int s = i >> 4, d = (i & 15) << 3;
    *(half8*)(K_lds + s*136 + d) =
        *(const half8*)(kvb + (size_t)(b*SKV_PAD + s)*2048 + h*128 + d);
  }
  __syncthreads();
  for (int c = 0; c < 4; ++c) {
    f32x4 acc[5][4] = {};
#pragma unroll
    for (int kt = 0; kt < 4; ++kt) {
      half8 af[5], bf[4];
#pragma unroll
      for (int m = 0; m < 5; ++m)
        af[m] = *(const half8*)(K_lds + (size_t)(m*16 + l4)*136 + kt*32 + lh*8);
#pragma unroll
      for (int n = 0; n < 4; ++n)
        bf[n] = *(const half8*)(Wqc + (size_t)(w*256 + c*64 + n*16 + l4)*1024 + h*128 + kt*32 + lh*8);
#pragma unroll
      for (int m = 0; m < 5; ++m)
#pragma unroll
        for (int n = 0; n < 4; ++n)
          acc[m][n] = __builtin_amdgcn_mfma_f32_16x16x32_f16(af[m], bf[n], acc[m][n], 0, 0, 0);
    }
#pragma unroll
    for (int n = 0; n < 4; ++n) {
      const int colk = w*256 + c*64 + n*16 + l4;
#pragma unroll
      for (int m = 0; m < 5; ++m)
#pragma unroll
        for (int j = 0; j < 4; ++j) {
          const int r = h*SKV_PAD + m*16 + lh*4 + j;
          size_t byte = ((size_t)(b*NKV_PAD + r))*2048 + (size_t)(colk >> 6)*128
                        + ((size_t)(((colk >> 3) & 7) ^ (r & 7)) << 4) + ((colk & 7) << 1);
          *(half_t*)((char*)Bt1 + byte) = (half_t)(acc[m][n][j]*ATTN_SCALE);
        }
    }
  }
}

__global__ __launch_bounds__(256, 2)
void w2_build(const half_t* __restrict__ kvb, const half_t* __restrict__ Wot,
              half_t* __restrict__ Bt2) {
  __shared__ half_t V_lds[80*136];
  const int blk = blockIdx.x;
  const int b = blk >> 3, h = blk & 7;
  const int tid = threadIdx.x;
  const int l = tid & 63, w = tid >> 6;
  const int l4 = l & 15, lh = l >> 4;
  for (int i = tid; i < 80*16; i += 256) {
    int s = i >> 4, d = (i & 15) << 3;
    *(half8*)(V_lds + s*136 + d) =
        *(const half8*)(kvb + (size_t)(b*SKV_PAD + s)*2048 + 1024 + h*128 + d);
  }
  __syncthreads();
  for (int c = 0; c < 4; ++c) {
    f32x4 acc[4][5] = {};
#pragma unroll
    for (int kt = 0; kt < 4; ++kt) {
      half8 af[4], bf[5];
#pragma unroll
      for (int m = 0; m < 4; ++m)
        af[m] = *(const half8*)(Wot + (size_t)(w*256 + c*64 + m*16 + l4)*1024 + h*128 + kt*32 + lh*8);
#pragma unroll
      for (int n = 0; n < 5; ++n)
        bf[n] = *(const half8*)(V_lds + (size_t)(n*16 + l4)*136 + kt*32 + lh*8);
#pragma unroll
      for (int m = 0; m < 4; ++m)
#pragma unroll
        for (int n = 0; n < 5; ++n)
          acc[m][n] = __builtin_amdgcn_mfma_f32_16x16x32_f16(af[m], bf[n], acc[m][n], 0, 0, 0);
    }
#pragma unroll
    for (int m = 0; m < 4; ++m) {
#pragma unroll
      for (int j = 0; j < 4; ++j) {
        const int nrow = w*256 + c*64 + m*16 + lh*4 + j;
        const size_t rowbase = ((size_t)(b*1024 + nrow))*1280;
#pragma unroll
        for (int n = 0; n < 5; ++n) {
          const int cc = h*80 + n*16 + l4;
          size_t byte = rowbase + (size_t)(cc >> 6)*128
                        + ((size_t)(((cc >> 3) & 7) ^ (nrow & 7)) << 4) + ((cc & 7) << 1);
          *(half_t*)((char*)Bt2 + byte) = (half_t)acc[m][n][j];
        }
      }
    }
  }
}

__global__ void c1_build(const half_t* __restrict__ kvb, const float* __restrict__ bq,
                         float* __restrict__ c1) {
  int idx = blockIdx.x * 256 + threadIdx.x;
  int b = idx / NKV, n = idx - b*NKV;
  int h = n / SKV_PAD, s = n - h*SKV_PAD;
  const half_t* kp = kvb + (size_t)(b*SKV_PAD + s)*2048 + h*128;
  float acc = 0.f;
#pragma unroll 8
  for (int d = 0; d < 128; ++d) acc += bq[h*128 + d] * (float)kp[d];
  c1[idx] = acc * ATTN_SCALE;
}

// ---------------- FUSED v4: 64-row tile, 16 waves (4/SIMD), depth-2 x pipeline ----------------
// 512 blocks (R14 grid/geometry). 1024 thr = 16 waves. S phase: wave = (head=w>>1,
// row-half=w&1), sacc[2][5]; paired waves' duplicate W1 frag reads hit the CU's L1.
// P phase: wave w owns out cols w*64, oacc[4][4] (W2 rows read once per block).
// x: per-thread f32x4 per kc, DEPTH-2 (load kc+2 at kc; write kc+1 at kc start).
// All swizzle math identical to R13/R14-verified paths.
__global__ __launch_bounds__(1024, 1)
void fused_sv(const float* __restrict__ X, const half_t* __restrict__ Bt1,
              const float* __restrict__ c1, const half_t* __restrict__ Bt2,
              const float* __restrict__ bo, float* __restrict__ out) {
  __shared__ half_t S_lds[64*640];       // 80 KB
  __shared__ half_t x_lds[2][64*64];     // 2 x 8 KB
  const int tid = threadIdx.x;
  const int l = tid & 63, w = tid >> 6;  // w 0..15
  const int l4 = l & 15, lh = l >> 4;
  const int k7 = l4 & 7;

  const int lin = ((int)blockIdx.x & 7)*64 + ((int)blockIdx.x >> 3);
  const int batch = lin >> 6;
  const int row0 = batch*SEQ_Q + (lin & 63)*64;
  const char* W1 = (const char*)(Bt1 + (size_t)batch*NKV_PAD*1024);
  const char* W2 = (const char*)(Bt2 + (size_t)batch*1024*NKV);
  const float* c1b = c1 + batch*NKV;

  // ================= S phase: head = w>>1, row-half rh = w&1 =================
  f32x4 sacc[2][5] = {};
  const int head = w >> 1, rh = w & 1;
  const int nfb = head*5;
  const int mrow0 = rh*32;

  // x staging: thread -> row tid>>4 (0..63), 4 floats at col (tid&15)*4; depth-2
  const int xrow = tid >> 4, xc4 = (tid & 15)*4;
  const float* xg = X + (size_t)(row0 + xrow)*1024 + xc4;
  f32x4 L0v, L1v;
  auto xload0 = [&](int kc) { L0v = *(const f32x4*)(xg + kc*64); };
  auto xload1 = [&](int kc) { L1v = *(const f32x4*)(xg + kc*64); };
  const int xslot = ((((xc4 >> 3) & 7) ^ (xrow & 7)) << 4) + (xc4 & 7)*2;
  auto xwrite0 = [&](int buf) {
    half_t h4[4];
#pragma unroll
    for (int e = 0; e < 4; ++e) h4[e] = (half_t)L0v[e];
    *(uint2*)((char*)x_lds[buf] + xrow*128 + xslot) = *(const uint2*)h4;
  };
  auto xwrite1 = [&](int buf) {
    half_t h4[4];
#pragma unroll
    for (int e = 0; e < 4; ++e) h4[e] = (half_t)L1v[e];
    *(uint2*)((char*)x_lds[buf] + xrow*128 + xslot) = *(const uint2*)h4;
  };

  half8 b0[5], b1[5];
  auto bload = [&](int t, half8* dst) {
    const int kc = t >> 1, kk = t & 1;
    const size_t koff = (size_t)kc*128 + (size_t)(((kk*4 + lh) ^ k7) << 4);
#pragma unroll
    for (int nf = 0; nf < 5; ++nf)
      dst[nf] = *(const half8*)(W1 + (size_t)((nfb + nf)*16 + l4)*2048 + koff);
  };
  auto smfma = [&](const half8* bf, int kc, int kk) {
    const char* xc = (const char*)x_lds[kc & 1];
    half8 af[2];
#pragma unroll
    for (int m = 0; m < 2; ++m)
      af[m] = *(const half8*)(xc + (size_t)(mrow0 + m*16 + l4)*128 + (((kk*4 + lh) ^ k7) << 4));
    __builtin_amdgcn_s_setprio(1);
#pragma unroll
    for (int nf = 0; nf < 5; ++nf)
#pragma unroll
      for (int m = 0; m < 2; ++m)
        sacc[m][nf] = __builtin_amdgcn_mfma_f32_16x16x32_f16(af[m], bf[nf], sacc[m][nf], 0, 0, 0);
    __builtin_amdgcn_s_setprio(0);
  };

  // prologue: x(0)->L0->buf0; x(1)->L1 (pending); B(0)
  xload0(0); xload1(1);
  xwrite0(0);
  bload(0, b0);
  asm volatile("s_waitcnt lgkmcnt(0)" ::: "memory");
  BAR();

  for (int kc = 0; kc < 16; ++kc) {
    // write x(kc+1) into buf (kc+1)&1 (slot parity: x(k) lives in L[k&1])
    if (kc + 1 < 16) {
      if ((kc + 1) & 1) xwrite1((kc + 1) & 1); else xwrite0((kc + 1) & 1);
    }
    // issue x(kc+2) into the slot just freed (L[kc&1])
    if (kc + 2 < 16) {
      if (kc & 1) xload1(kc + 2); else xload0(kc + 2);
    }
    bload(2*kc + 1, b1);
    smfma(b0, kc, 0);
    if (2*kc + 2 < 32) bload(2*kc + 2, b0);
    smfma(b1, kc, 1);
    if (kc + 1 < 16) {
      asm volatile("s_waitcnt lgkmcnt(0)" ::: "memory");
      BAR();
    }
  }

  // dump S-frags to S_lds (3-bit swizzle; verified)
#pragma unroll
  for (int nf = 0; nf < 5; ++nf) {
    const int col = (nfb + nf)*16 + l4;
#pragma unroll
    for (int m = 0; m < 2; ++m)
#pragma unroll
      for (int j = 0; j < 4; ++j) {
        const int row = mrow0 + m*16 + lh*4 + j;
        size_t byte = (size_t)row*1280 + (size_t)(col >> 6)*128
                      + ((size_t)(((col >> 3) & 7) ^ (row & 7)) << 4) + ((col & 7) << 1);
        *(half_t*)((char*)S_lds + byte) = (half_t)sacc[m][nf][j];
      }
  }
  asm volatile("s_waitcnt lgkmcnt(0)" ::: "memory");
  BAR();

  // ================= softmax in LDS (verified; 512 active threads) =================
  if (tid < 512) {
    const int row = tid >> 3, h = tid & 7;
    const int key = row & 7;
    char* base = (char*)S_lds + (size_t)row*1280;
    float fv[10][8];
    float mx = -1e30f;
#pragma unroll
    for (int i = 0; i < 10; ++i) {
      const int ls = h*10 + i;
      half8 v = *(const half8*)(base + (size_t)(ls >> 3)*128 + ((size_t)((ls & 7) ^ key) << 4));
      f32x4 ca = *(const f32x4*)(c1b + h*80 + i*8);
      f32x4 cb = *(const f32x4*)(c1b + h*80 + i*8 + 4);
#pragma unroll
      for (int j = 0; j < 8; ++j) {
        const float cc = (j < 4) ? ca[j] : cb[j - 4];
        const float sv = (float)v[j] + cc;
        const bool ok = (i*8 + j) < SEQ_KV;
        fv[i][j] = ok ? sv : -1e30f;
        if (ok) mx = fmaxf(mx, sv);
      }
    }
    float sm = 0.f;
#pragma unroll
    for (int i = 0; i < 10; ++i)
#pragma unroll
      for (int j = 0; j < 8; ++j) { float e = __expf(fv[i][j] - mx); sm += e; fv[i][j] = e; }
    const float inv = 1.f / sm;
#pragma unroll
    for (int i = 0; i < 10; ++i) {
      const int ls = h*10 + i;
      half8 t;
#pragma unroll
      for (int j = 0; j < 8; ++j) t[j] = (half_t)(fv[i][j] * inv);
      *(half8*)(base + (size_t)(ls >> 3)*128 + ((size_t)((ls & 7) ^ key) << 4)) = t;
    }
  }
  asm volatile("s_waitcnt lgkmcnt(0)" ::: "memory");
  BAR();

  // ================= P phase: wave w -> out cols w*64, oacc[4][4], depth-1 B prefetch ====
  {
    f32x4 oacc[4][4] = {};
    half8 p0[4], p1[4];
    const int ncb = w*64;
    auto pbload = [&](int ks, half8* dst) {
      const size_t koff = (size_t)(ks >> 1)*128 + (size_t)((((ks & 1)*4 + lh) ^ k7) << 4);
#pragma unroll
      for (int nf = 0; nf < 4; ++nf)
        dst[nf] = *(const half8*)(W2 + (size_t)(ncb + nf*16 + l4)*1280 + koff);
    };
    auto pmfma = [&](const half8* bf, int ks) {
      const size_t koff = (size_t)(ks >> 1)*128 + (size_t)((((ks & 1)*4 + lh) ^ k7) << 4);
      half8 af[4];
#pragma unroll
      for (int m = 0; m < 4; ++m)
        af[m] = *(const half8*)((const char*)S_lds + (size_t)(m*16 + l4)*1280 + koff);
      __builtin_amdgcn_s_setprio(1);
#pragma unroll
      for (int nf = 0; nf < 4; ++nf)
#pragma unroll
        for (int m = 0; m < 4; ++m)
          oacc[m][nf] = __builtin_amdgcn_mfma_f32_16x16x32_f16(af[m], bf[nf], oacc[m][nf], 0, 0, 0);
      __builtin_amdgcn_s_setprio(0);
    };

    pbload(0, p0);
    for (int ks = 0; ks < 20; ks += 2) {
      pbload(ks + 1, p1);
      pmfma(p0, ks);
      if (ks + 2 < 20) pbload(ks + 2, p0);
      pmfma(p1, ks + 1);
    }

#pragma unroll
    for (int nf = 0; nf < 4; ++nf) {
      const int col = ncb + nf*16 + l4;
      const float bvv = bo[col];
#pragma unroll
      for (int m = 0; m < 4; ++m)
#pragma unroll
        for (int j = 0; j < 4; ++j) {
          const int row = row0 + m*16 + lh*4 + j;
          out[(size_t)row*1024 + col] = oacc[m][nf][j] + bvv;
        }
    }
  }
}

// ---------------- launch ----------------
extern "C" void kernel_launch(void* const* d_in, const int* in_sizes, int n_in,
                              void* d_out, int out_size, void* d_ws, size_t ws_size,
                              hipStream_t stream) {
  (void)in_sizes; (void)n_in; (void)out_size; (void)ws_size;
  const float* x  = (const float*)d_in[0];
  const float* y  = (const float*)d_in[1];
  const float* Wq = (const float*)d_in[2];
  const float* bq = (const float*)d_in[3];
  const float* Wk = (const float*)d_in[4];
  const float* bk = (const float*)d_in[5];
  const float* Wv = (const float*)d_in[6];
  const float* bv = (const float*)d_in[7];
  const float* Wo = (const float*)d_in[8];
  const float* bo = (const float*)d_in[9];

  char* ws = (char*)d_ws;
  half_t* Wqc  = (half_t*)(ws + WS_WQC);
  half_t* Wot  = (half_t*)(ws + WS_WOT);
  half_t* Wkvt = (half_t*)(ws + WS_WKVT);
  half_t* yh   = (half_t*)(ws + WS_YH);
  half_t* kvb  = (half_t*)(ws + WS_KV);
  float*  bkv  = (float*)(ws + WS_BKV);
  half_t* Bt1  = (half_t*)(ws + WS_BT1);
  half_t* Bt2  = (half_t*)(ws + WS_BT2);
  float*  c1   = (float*)(ws + WS_C1);

  dim3 tb(32, 8);
  cast_f32_f16<<<512, 256, 0, stream>>>(Wq, Wqc);
  transpose_f32f16<<<dim3(32, 32), tb, 0, stream>>>(Wo, Wot, 1024, 1024);
  transpose_f32f16<<<dim3(32, 24), tb, 0, stream>>>(Wk, Wkvt, 768, 1024);
  transpose_f32f16<<<dim3(32, 24), tb, 0, stream>>>(Wv, Wkvt + (size_t)1024*768, 768, 1024);
  convert_pad_y<<<BATCH*SKV_PAD*D_CROSS/256, 256, 0, stream>>>(y, yh);
  concat_bias<<<2*D_EMBED/256, 256, 0, stream>>>(bk, bv, bkv);

  // K/V projection
  gemm_kv<<<dim3(16, 5), 256, 0, stream>>>(yh, Wkvt, bkv, kvb, BATCH*SKV_PAD, 2048, 768);

  // folded-weight builders
  c1_build<<<BATCH*NKV/256, 256, 0, stream>>>(kvb, bq, c1);
  w1_build<<<BATCH*N_HEADS, 256, 0, stream>>>(kvb, Wqc, Bt1);
  w2_build<<<BATCH*N_HEADS, 256, 0, stream>>>(kvb, Wot, Bt2);

  // fused S-GEMM + softmax + out-GEMM (S stays in LDS), 64-row tiles, 16 waves
  fused_sv<<<512, 1024, 0, stream>>>(x, Bt1, c1, Bt2, bo, (float*)d_out);
}

// Round 17
// 247.660 us; speedup vs baseline: 1.4124x; 1.2007x over previous
//
#include <hip/hip_runtime.h>

typedef _Float16 half_t;
typedef _Float16 half8 __attribute__((ext_vector_type(8)));
typedef float f32x4 __attribute__((ext_vector_type(4)));

#define D_EMBED   1024
#define D_CROSS   768
#define N_HEADS   8
#define D_HEAD    128
#define BATCH     8
#define SEQ_Q     4096
#define SEQ_KV    77
#define SKV_PAD   80
#define NKV       (N_HEADS*SKV_PAD)     /* 640 */
#define NKV_PAD   768                   /* Bt1 row-dim padding (rows 640..767 never read) */
#define M_Q       (BATCH*SEQ_Q)         /* 32768 */

// ---------------- workspace layout (bytes) ----------------
#define WS_S     ((size_t)0)                                   // (unused)
#define WS_WQC   (WS_S    + (size_t)M_Q*NKV*2)
#define WS_WOT   (WS_WQC  + (size_t)D_EMBED*D_EMBED*2)
#define WS_WKVT  (WS_WOT  + (size_t)D_EMBED*D_EMBED*2)
#define WS_YH    (WS_WKVT + (size_t)2*D_EMBED*D_CROSS*2)
#define WS_KV    (WS_YH   + (size_t)BATCH*SKV_PAD*D_CROSS*2)
#define WS_BKV   (WS_KV   + (size_t)BATCH*SKV_PAD*2*D_EMBED*2)
#define WS_BT1   (WS_BKV  + (size_t)2*D_EMBED*4)               // W1^T fp16 [8][768][1024] PLAIN
#define WS_BT2   (WS_BT1  + (size_t)BATCH*NKV_PAD*D_EMBED*2)   // W2^T fp16 [8][1024][640] PLAIN
#define WS_C1    (WS_BT2  + (size_t)BATCH*D_EMBED*NKV*2)       // c1 fp32 [8][640]

#define ATTN_SCALE 0.08838834764831845f

__device__ __forceinline__ void gload_lds16(const void* g, void* lds) {
  __builtin_amdgcn_global_load_lds(
      (const __attribute__((address_space(1))) unsigned int*)g,
      (__attribute__((address_space(3))) unsigned int*)lds, 16, 0, 0);
}
__device__ __forceinline__ void BAR() {
  __builtin_amdgcn_s_barrier();
  __builtin_amdgcn_sched_barrier(0);
}

// ---------------- prep kernels ----------------
__global__ void cast_f32_f16(const float* __restrict__ src, half_t* __restrict__ dst) {
  int i = blockIdx.x * 256 + threadIdx.x;
  f32x4 a = *(const f32x4*)(src + (size_t)i*8);
  f32x4 b = *(const f32x4*)(src + (size_t)i*8 + 4);
  half8 h;
#pragma unroll
  for (int j = 0; j < 4; ++j) { h[j] = (half_t)a[j]; h[j+4] = (half_t)b[j]; }
  *(half8*)(dst + (size_t)i*8) = h;
}

__global__ void transpose_f32f16(const float* __restrict__ src, half_t* __restrict__ dst,
                                 int K, int N) {
  __shared__ float tile[32][33];
  int n0 = blockIdx.x * 32, k0 = blockIdx.y * 32;
  int tx = threadIdx.x, ty = threadIdx.y;
#pragma unroll
  for (int j = 0; j < 4; ++j)
    tile[ty + j*8][tx] = src[(size_t)(k0 + ty + j*8)*N + n0 + tx];
  __syncthreads();
#pragma unroll
  for (int j = 0; j < 4; ++j)
    dst[(size_t)(n0 + ty + j*8)*K + k0 + tx] = (half_t)tile[tx][ty + j*8];
}

__global__ void convert_pad_y(const float* __restrict__ y, half_t* __restrict__ yh) {
  int idx = blockIdx.x * 256 + threadIdx.x;
  int r = idx / D_CROSS, col = idx - r*D_CROSS;
  int b = r / SKV_PAD, s = r - b*SKV_PAD;
  yh[idx] = (s < SEQ_KV) ? (half_t)y[(size_t)(b*SEQ_KV + s)*D_CROSS + col] : (half_t)0.f;
}

__global__ void concat_bias(const float* __restrict__ bk, const float* __restrict__ bv,
                            float* __restrict__ bkv) {
  int i = blockIdx.x * 256 + threadIdx.x;
  bkv[i] = (i < D_EMBED) ? bk[i] : bv[i - D_EMBED];
}

// ---------------- 128x128 GEMM — K/V projection (R7-verified) ----------------
__global__ __launch_bounds__(256, 3)
void gemm_kv(const half_t* __restrict__ A, const half_t* __restrict__ Bt,
             const float* __restrict__ bias, half_t* __restrict__ C,
             int M, int N, int K) {
  __shared__ half_t As[3][128*32];
  __shared__ half_t Bs[2][128*32];
  const int tid = threadIdx.x;
  const int l = tid & 63, w = tid >> 6;
  const int l4 = l & 15, lh = l >> 4;
  const int bn0 = blockIdx.x * 128, bm0 = blockIdx.y * 128;
  const int wr = w >> 1, wc = w & 1;
  const int rslot = lh << 4;
  f32x4 acc[4][4] = {};
  const int nk = K >> 5;
  const int srow = w*16 + (l >> 2);
  const int scol = (l & 3)*8;

  auto stageB = [&](int kt, int bb) {
    const half_t* g = Bt + (size_t)(bn0 + srow)*K + scol + kt*32;
    gload_lds16(g,                 (char*)Bs[bb] + w*1024);
    gload_lds16(g + (size_t)64*K,  (char*)Bs[bb] + 4096 + w*1024);
  };
  auto stageA = [&](int kt, int bb) {
    const half_t* g = A + (size_t)(bm0 + srow)*K + scol + kt*32;
    gload_lds16(g,                 (char*)As[bb] + w*1024);
    gload_lds16(g + (size_t)64*K,  (char*)As[bb] + 4096 + w*1024);
  };
  auto compute = [&](int ab, int bb) {
    half8 af[4], bf[4];
#pragma unroll
    for (int m = 0; m < 4; ++m)
      af[m] = *(const half8*)((const char*)As[ab] + (size_t)(wr*64 + m*16 + l4)*64 + rslot);
#pragma unroll
    for (int n = 0; n < 4; ++n)
      bf[n] = *(const half8*)((const char*)Bs[bb] + (size_t)(wc*64 + n*16 + l4)*64 + rslot);
#pragma unroll
    for (int m = 0; m < 4; ++m)
#pragma unroll
      for (int n = 0; n < 4; ++n)
        acc[m][n] = __builtin_amdgcn_mfma_f32_16x16x32_f16(af[m], bf[n], acc[m][n], 0, 0, 0);
  };

  stageA(0, 0); stageA(1, 1); stageB(0, 0);
  asm volatile("s_waitcnt vmcnt(0)" ::: "memory");
  BAR();
  int aCur = 0, aP2 = 2;
  for (int t = 0; t < nk; ++t) {
    if (t + 1 < nk) stageB(t + 1, (t + 1) & 1);
    if (t + 2 < nk) stageA(t + 2, aP2);
    compute(aCur, t & 1);
    if (t + 1 < nk) {
      if (t + 2 < nk) { asm volatile("s_waitcnt vmcnt(2)" ::: "memory"); }
      else            { asm volatile("s_waitcnt vmcnt(0)" ::: "memory"); }
      BAR();
    }
    aCur = (aCur == 2) ? 0 : aCur + 1;
    aP2  = (aP2  == 2) ? 0 : aP2  + 1;
  }

  const int cb = bn0 + wc*64, rb = bm0 + wr*64;
#pragma unroll
  for (int n = 0; n < 4; ++n) {
    const int col = cb + n*16 + l4;
    const float bvv = bias[col];
#pragma unroll
    for (int m = 0; m < 4; ++m)
#pragma unroll
      for (int j = 0; j < 4; ++j)
        C[(size_t)(rb + m*16 + lh*4 + j)*N + col] = (half_t)(acc[m][n][j] + bvv);
  }
}

// ---------------- builders (PLAIN global layouts now) ----------------
__global__ __launch_bounds__(256, 2)
void w1_build(const half_t* __restrict__ kvb, const half_t* __restrict__ Wqc,
              half_t* __restrict__ Bt1) {
  __shared__ half_t K_lds[80*136];
  const int blk = blockIdx.x;
  const int b = blk >> 3, h = blk & 7;
  const int tid = threadIdx.x;
  const int l = tid & 63, w = tid >> 6;
  const int l4 = l & 15, lh = l >> 4;
  for (int i = tid; i < 80*16; i += 256) {
    int s = i >> 4, d = (i & 15) << 3;
    *(half8*)(K_lds + s*136 + d) =
        *(const half8*)(kvb + (size_t)(b*SKV_PAD + s)*2048 + h*128 + d);
  }
  __syncthreads();
  for (int c = 0; c < 4; ++c) {
    f32x4 acc[5][4] = {};
#pragma unroll
    for (int kt = 0; kt < 4; ++kt) {
      half8 af[5], bf[4];
#pragma unroll
      for (int m = 0; m < 5; ++m)
        af[m] = *(const half8*)(K_lds + (size_t)(m*16 + l4)*136 + kt*32 + lh*8);
#pragma unroll
      for (int n = 0; n < 4; ++n)
        bf[n] = *(const half8*)(Wqc + (size_t)(w*256 + c*64 + n*16 + l4)*1024 + h*128 + kt*32 + lh*8);
#pragma unroll
      for (int m = 0; m < 5; ++m)
#pragma unroll
        for (int n = 0; n < 4; ++n)
          acc[m][n] = __builtin_amdgcn_mfma_f32_16x16x32_f16(af[m], bf[n], acc[m][n], 0, 0, 0);
    }
#pragma unroll
    for (int n = 0; n < 4; ++n) {
      const int colk = w*256 + c*64 + n*16 + l4;
#pragma unroll
      for (int m = 0; m < 5; ++m)
#pragma unroll
        for (int j = 0; j < 4; ++j) {
          const int r = h*SKV_PAD + m*16 + lh*4 + j;
          Bt1[((size_t)(b*NKV_PAD + r))*1024 + colk] = (half_t)(acc[m][n][j]*ATTN_SCALE);
        }
    }
  }
}

__global__ __launch_bounds__(256, 2)
void w2_build(const half_t* __restrict__ kvb, const half_t* __restrict__ Wot,
              half_t* __restrict__ Bt2) {
  __shared__ half_t V_lds[80*136];
  const int blk = blockIdx.x;
  const int b = blk >> 3, h = blk & 7;
  const int tid = threadIdx.x;
  const int l = tid & 63, w = tid >> 6;
  const int l4 = l & 15, lh = l >> 4;
  for (int i = tid; i < 80*16; i += 256) {
    int s = i >> 4, d = (i & 15) << 3;
    *(half8*)(V_lds + s*136 + d) =
        *(const half8*)(kvb + (size_t)(b*SKV_PAD + s)*2048 + 1024 + h*128 + d);
  }
  __syncthreads();
  for (int c = 0; c < 4; ++c) {
    f32x4 acc[4][5] = {};
#pragma unroll
    for (int kt = 0; kt < 4; ++kt) {
      half8 af[4], bf[5];
#pragma unroll
      for (int m = 0; m < 4; ++m)
        af[m] = *(const half8*)(Wot + (size_t)(w*256 + c*64 + m*16 + l4)*1024 + h*128 + kt*32 + lh*8);
#pragma unroll
      for (int n = 0; n < 5; ++n)
        bf[n] = *(const half8*)(V_lds + (size_t)(n*16 + l4)*136 + kt*32 + lh*8);
#pragma unroll
      for (int m = 0; m < 4; ++m)
#pragma unroll
        for (int n = 0; n < 5; ++n)
          acc[m][n] = __builtin_amdgcn_mfma_f32_16x16x32_f16(af[m], bf[n], acc[m][n], 0, 0, 0);
    }
#pragma unroll
    for (int m = 0; m < 4; ++m) {
#pragma unroll
      for (int j = 0; j < 4; ++j) {
        const int nrow = w*256 + c*64 + m*16 + lh*4 + j;
#pragma unroll
        for (int n = 0; n < 5; ++n) {
          const int cc = h*80 + n*16 + l4;
          Bt2[((size_t)(b*1024 + nrow))*640 + cc] = (half_t)acc[m][n][j];
        }
      }
    }
  }
}

__global__ void c1_build(const half_t* __restrict__ kvb, const float* __restrict__ bq,
                         float* __restrict__ c1) {
  int idx = blockIdx.x * 256 + threadIdx.x;
  int b = idx / NKV, n = idx - b*NKV;
  int h = n / SKV_PAD, s = n - h*SKV_PAD;
  const half_t* kp = kvb + (size_t)(b*SKV_PAD + s)*2048 + h*128;
  float acc = 0.f;
#pragma unroll 8
  for (int d = 0; d < 128; ++d) acc += bq[h*128 + d] * (float)kp[d];
  c1[idx] = acc * ATTN_SCALE;
}

// ---------------- FUSED v5: all B-operands via LDS (coalesced reg-staging) ----------------
// 512 blocks, 512 thr / 8 waves (R14 skeleton). S stays in sacc registers until dump.
// LDS (144 KB union):
//   S phase: Bbuf0 @0, Bbuf1 @51200 (640 rows x 80B padded, conflict-free reads),
//            xbuf0 @102400, xbuf1 @110592 (R14-verified XOR layout)
//   P phase: S_lds @0 (80 KB, R14-verified XOR layout), Wbuf @81920 (1024 rows x 64B, 2-bit XOR)
// B loads issued 2 steps ahead into regs (T14), written after the consuming barrier.
__global__ __launch_bounds__(512, 1)
void fused_sv(const float* __restrict__ X, const half_t* __restrict__ Bt1,
              const float* __restrict__ c1, const half_t* __restrict__ Bt2,
              const float* __restrict__ bo, float* __restrict__ out) {
  __shared__ char LDS[147456];
  char* const Bb0 = LDS;
  char* const Bb1 = LDS + 51200;
  char* const Xb0 = LDS + 102400;
  char* const Xb1 = LDS + 110592;
  char* const SL  = LDS;            // P phase
  char* const WB  = LDS + 81920;    // P phase

  const int tid = threadIdx.x;
  const int l = tid & 63, w = tid >> 6;
  const int l4 = l & 15, lh = l >> 4;
  const int k7 = l4 & 7;

  const int lin = ((int)blockIdx.x & 7)*64 + ((int)blockIdx.x >> 3);
  const int batch = lin >> 6;
  const int row0 = batch*SEQ_Q + (lin & 63)*64;
  const half_t* W1 = Bt1 + (size_t)batch*NKV_PAD*1024;   // plain, 1024-half rows
  const half_t* W2 = Bt2 + (size_t)batch*1024*NKV;       // plain, 640-half rows
  const float* c1b = c1 + batch*NKV;

  // ================= S phase: wave = head, sacc[4][5] =================
  f32x4 sacc[4][5] = {};
  const int nfb = w*5;

  // x staging (R14-verified math): row tid>>3, 8 floats at col (tid&7)*8
  const int xrow = tid >> 3, xc8 = tid & 7;
  const float* xg = X + (size_t)(row0 + xrow)*1024 + xc8*8;
  f32x4 xa, xb;
  auto xload = [&](int xc) {
    const float* g = xg + xc*64;
    xa = *(const f32x4*)g; xb = *(const f32x4*)(g + 4);
  };
  const int xslot = ((xc8 ^ (xrow & 7)) << 4);
  auto xwrite = [&](char* buf) {
    half8 h;
#pragma unroll
    for (int e = 0; e < 4; ++e) { h[e] = (half_t)xa[e]; h[e+4] = (half_t)xb[e]; }
    *(half8*)(buf + xrow*128 + xslot) = h;
  };

  // B staging: 5 slots/thread, s = i*512 + tid; row = 128i + (tid>>2), slot = tid&3
  half8 Br[5];
  const int brow0s = tid >> 2;           // 0..127
  const int bslot = tid & 3;
  auto bload = [&](int kc) {             // kc = 32-col chunk index, 0..31
    const half_t* g = W1 + (size_t)brow0s*1024 + kc*32 + bslot*8;
#pragma unroll
    for (int i = 0; i < 5; ++i)
      Br[i] = *(const half8*)(g + (size_t)i*128*1024);
  };
  auto bwrite = [&](char* buf) {
#pragma unroll
    for (int i = 0; i < 5; ++i)
      *(half8*)(buf + (size_t)(i*128 + brow0s)*80 + bslot*16) = Br[i];
  };

  auto smfma = [&](const char* bbuf, const char* xbuf, int kk) {
    half8 bf[5], af[4];
#pragma unroll
    for (int nf = 0; nf < 5; ++nf)
      bf[nf] = *(const half8*)(bbuf + (size_t)((nfb + nf)*16 + l4)*80 + lh*16);
#pragma unroll
    for (int m = 0; m < 4; ++m)
      af[m] = *(const half8*)(xbuf + (size_t)(m*16 + l4)*128 + (((kk*4 + lh) ^ k7) << 4));
    __builtin_amdgcn_s_setprio(1);
#pragma unroll
    for (int nf = 0; nf < 5; ++nf)
#pragma unroll
      for (int m = 0; m < 4; ++m)
        sacc[m][nf] = __builtin_amdgcn_mfma_f32_16x16x32_f16(af[m], bf[nf], sacc[m][nf], 0, 0, 0);
    __builtin_amdgcn_s_setprio(0);
  };

  // prologue: B(0)->Bb0; B(1) in regs; x(0)->Xb0; x(1) in regs
  bload(0); bwrite(Bb0); bload(1);
  xload(0); xwrite(Xb0); xload(1);
  asm volatile("s_waitcnt lgkmcnt(0)" ::: "memory");
  BAR();

  for (int kc = 0; kc < 32; ++kc) {
    char* const bcur = (kc & 1) ? Bb1 : Bb0;
    char* const bnxt = (kc & 1) ? Bb0 : Bb1;
    char* const xcur = ((kc >> 1) & 1) ? Xb1 : Xb0;
    // write B(kc+1) (in regs) into the other buffer; issue B(kc+2)
    if (kc + 1 < 32) {
      bwrite(bnxt);
      if (kc + 2 < 32) bload(kc + 2);
    }
    // x: at the second half of each x-chunk, write x(xc+1) and issue x(xc+2)
    if ((kc & 1) == 1 && kc + 1 < 32) {
      char* const xnxt = (((kc + 1) >> 1) & 1) ? Xb1 : Xb0;
      xwrite(xnxt);
      if (kc + 3 < 32) xload((kc + 3) >> 1);
    }
    smfma(bcur, xcur, kc & 1);
    asm volatile("s_waitcnt lgkmcnt(0)" ::: "memory");
    BAR();
  }

  // issue W2(0) loads early (regs), then dump S to S_lds (R14-verified XOR layout)
  half8 Wr[8];
  const int wrow0s = tid >> 2;           // 0..127
  const int wslotP = tid & 3;
  auto wload = [&](int ks) {             // ks = 32-col chunk of the 640 k-dim, 0..19
    const half_t* g = W2 + (size_t)wrow0s*640 + ks*32 + wslotP*8;
#pragma unroll
    for (int i = 0; i < 8; ++i)
      Wr[i] = *(const half8*)(g + (size_t)i*128*640);
  };
  auto wwrite = [&]() {
#pragma unroll
    for (int i = 0; i < 8; ++i) {
      const int n = i*128 + wrow0s;
      *(half8*)(WB + (size_t)n*64 + ((wslotP ^ (n & 3)) << 4)) = Wr[i];
    }
  };

  wload(0);

#pragma unroll
  for (int nf = 0; nf < 5; ++nf) {
    const int col = (nfb + nf)*16 + l4;
#pragma unroll
    for (int m = 0; m < 4; ++m)
#pragma unroll
      for (int j = 0; j < 4; ++j) {
        const int row = m*16 + lh*4 + j;
        size_t byte = (size_t)row*1280 + (size_t)(col >> 6)*128
                      + ((size_t)(((col >> 3) & 7) ^ (row & 7)) << 4) + ((col & 7) << 1);
        *(half_t*)(SL + byte) = (half_t)sacc[m][nf][j];
      }
  }
  asm volatile("s_waitcnt lgkmcnt(0)" ::: "memory");
  BAR();

  // W2(0) into Wbuf (region disjoint from S_lds), then softmax in parallel region
  wwrite();
  wload(1);

  // ================= softmax in S_lds (R14-verified) =================
  {
    const int row = tid >> 3, h = tid & 7;
    const int key = row & 7;
    char* base = SL + (size_t)row*1280;
    float fv[10][8];
    float mx = -1e30f;
#pragma unroll
    for (int i = 0; i < 10; ++i) {
      const int ls = h*10 + i;
      half8 v = *(const half8*)(base + (size_t)(ls >> 3)*128 + ((size_t)((ls & 7) ^ key) << 4));
      f32x4 ca = *(const f32x4*)(c1b + h*80 + i*8);
      f32x4 cb = *(const f32x4*)(c1b + h*80 + i*8 + 4);
#pragma unroll
      for (int j = 0; j < 8; ++j) {
        const float cc = (j < 4) ? ca[j] : cb[j - 4];
        const float sv = (float)v[j] + cc;
        const bool ok = (i*8 + j) < SEQ_KV;
        fv[i][j] = ok ? sv : -1e30f;
        if (ok) mx = fmaxf(mx, sv);
      }
    }
    float sm = 0.f;
#pragma unroll
    for (int i = 0; i < 10; ++i)
#pragma unroll
      for (int j = 0; j < 8; ++j) { float e = __expf(fv[i][j] - mx); sm += e; fv[i][j] = e; }
    const float inv = 1.f / sm;
#pragma unroll
    for (int i = 0; i < 10; ++i) {
      const int ls = h*10 + i;
      half8 t;
#pragma unroll
      for (int j = 0; j < 8; ++j) t[j] = (half_t)(fv[i][j] * inv);
      *(half8*)(base + (size_t)(ls >> 3)*128 + ((size_t)((ls & 7) ^ key) << 4)) = t;
    }
  }
  asm volatile("s_waitcnt lgkmcnt(0)" ::: "memory");
  BAR();

  // ================= P phase: wave w -> out cols w*128, oacc[4][8]; W2 via Wbuf =================
  {
    f32x4 oacc[4][8] = {};
    const int ncb = w*128;

    for (int ks = 0; ks < 20; ++ks) {
      const size_t koff = (size_t)(ks >> 1)*128 + (size_t)((((ks & 1)*4 + lh) ^ k7) << 4);
      half8 af[4], bf[8];
#pragma unroll
      for (int m = 0; m < 4; ++m)
        af[m] = *(const half8*)(SL + (size_t)(m*16 + l4)*1280 + koff);
#pragma unroll
      for (int nf = 0; nf < 8; ++nf) {
        const int r = ncb + nf*16 + l4;
        bf[nf] = *(const half8*)(WB + (size_t)r*64 + ((lh ^ (r & 3)) << 4));
      }
      __builtin_amdgcn_s_setprio(1);
#pragma unroll
      for (int nf = 0; nf < 8; ++nf)
#pragma unroll
        for (int m = 0; m < 4; ++m)
          oacc[m][nf] = __builtin_amdgcn_mfma_f32_16x16x32_f16(af[m], bf[nf], oacc[m][nf], 0, 0, 0);
      __builtin_amdgcn_s_setprio(0);

      if (ks + 1 < 20) {
        BAR();                               // everyone done reading Wbuf(ks)
        wwrite();                            // Wbuf <- W2(ks+1)
        if (ks + 2 < 20) wload(ks + 2);
        asm volatile("s_waitcnt lgkmcnt(0)" ::: "memory");
        BAR();
      }
    }

    // epilogue (R13-verified)
#pragma unroll
    for (int nf = 0; nf < 8; ++nf) {
      const int col = ncb + nf*16 + l4;
      const float bvv = bo[col];
#pragma unroll
      for (int m = 0; m < 4; ++m)
#pragma unroll
        for (int j = 0; j < 4; ++j) {
          const int row = row0 + m*16 + lh*4 + j;
          out[(size_t)row*1024 + col] = oacc[m][nf][j] + bvv;
        }
    }
  }
}

// ---------------- launch ----------------
extern "C" void kernel_launch(void* const* d_in, const int* in_sizes, int n_in,
                              void* d_out, int out_size, void* d_ws, size_t ws_size,
                              hipStream_t stream) {
  (void)in_sizes; (void)n_in; (void)out_size; (void)ws_size;
  const float* x  = (const float*)d_in[0];
  const float* y  = (const float*)d_in[1];
  const float* Wq = (const float*)d_in[2];
  const float* bq = (const float*)d_in[3];
  const float* Wk = (const float*)d_in[4];
  const float* bk = (const float*)d_in[5];
  const float* Wv = (const float*)d_in[6];
  const float* bv = (const float*)d_in[7];
  const float* Wo = (const float*)d_in[8];
  const float* bo = (const float*)d_in[9];

  char* ws = (char*)d_ws;
  half_t* Wqc  = (half_t*)(ws + WS_WQC);
  half_t* Wot  = (half_t*)(ws + WS_WOT);
  half_t* Wkvt = (half_t*)(ws + WS_WKVT);
  half_t* yh   = (half_t*)(ws + WS_YH);
  half_t* kvb  = (half_t*)(ws + WS_KV);
  float*  bkv  = (float*)(ws + WS_BKV);
  half_t* Bt1  = (half_t*)(ws + WS_BT1);
  half_t* Bt2  = (half_t*)(ws + WS_BT2);
  float*  c1   = (float*)(ws + WS_C1);

  dim3 tb(32, 8);
  cast_f32_f16<<<512, 256, 0, stream>>>(Wq, Wqc);
  transpose_f32f16<<<dim3(32, 32), tb, 0, stream>>>(Wo, Wot, 1024, 1024);
  transpose_f32f16<<<dim3(32, 24), tb, 0, stream>>>(Wk, Wkvt, 768, 1024);
  transpose_f32f16<<<dim3(32, 24), tb, 0, stream>>>(Wv, Wkvt + (size_t)1024*768, 768, 1024);
  convert_pad_y<<<BATCH*SKV_PAD*D_CROSS/256, 256, 0, stream>>>(y, yh);
  concat_bias<<<2*D_EMBED/256, 256, 0, stream>>>(bk, bv, bkv);

  // K/V projection
  gemm_kv<<<dim3(16, 5), 256, 0, stream>>>(yh, Wkvt, bkv, kvb, BATCH*SKV_PAD, 2048, 768);

  // folded-weight builders (plain layouts)
  c1_build<<<BATCH*NKV/256, 256, 0, stream>>>(kvb, bq, c1);
  w1_build<<<BATCH*N_HEADS, 256, 0, stream>>>(kvb, Wqc, Bt1);
  w2_build<<<BATCH*N_HEADS, 256, 0, stream>>>(kvb, Wot, Bt2);

  // fused S-GEMM + softmax + out-GEMM, all MFMA operands via LDS
  fused_sv<<<512, 512, 0, stream>>>(x, Bt1, c1, Bt2, bo, (float*)d_out);
}